// Round 1
// baseline (501.006 us; speedup 1.0000x reference)
//
#include <hip/hip_runtime.h>
#include <hip/hip_cooperative_groups.h>

namespace cg = cooperative_groups;

#define B_SZ 8
#define L_SEQ 144
#define NTOK 1152
#define D_MODEL 256
#define D_INNER 512
#define D_STATE 64
#define DT_RANK 4
#define NDBC 132

#define BM 64
#define BN 64
#define BK 16

// ---------------------------------------------------------------------------
// GEMM tile (device): C[m0:+64, n0:+64] = A·B over k in [kbeg,kend)
//  A_MK=true : A stored [m][k] ; false: A stored [k][m].  B always [n][k].
//  GN: guard n<N on B-loads / C-stores (N=132 case).
//  Next k-slab's global loads are prefetched before the FMA loop so the
//  load latency hides under compute even at ~1 busy block/CU.
// ---------------------------------------------------------------------------
template<bool A_MK, bool GN>
__device__ __forceinline__ void gemm_tile(const float* __restrict__ A,
                                          const float* __restrict__ Bm,
                                          float* __restrict__ C,
                                          const int N, const int lda, const int ldb,
                                          const int ldc, const int m0, const int n0,
                                          const int kbeg, const int kend,
                                          float (*__restrict__ As)[BM + 4],
                                          float (*__restrict__ Bs)[BN + 4],
                                          const int tid) {
    const int ty = tid >> 4, tx = tid & 15;
    const int lrow = tid >> 2, kq = (tid & 3) * 4;   // transpose-load indices
    const int kk = tid >> 4, cc = (tid & 15) * 4;    // direct-load indices
    float acc[4][4] = {};
    float4 av, bv;
    if (A_MK) av = *(const float4*)(A + (size_t)(m0 + lrow) * lda + kbeg + kq);
    else      av = *(const float4*)(A + (size_t)(kbeg + kk) * lda + m0 + cc);
    bv = make_float4(0.f, 0.f, 0.f, 0.f);
    if (!GN || (n0 + lrow) < N)
        bv = *(const float4*)(Bm + (size_t)(n0 + lrow) * ldb + kbeg + kq);

    for (int k0 = kbeg; k0 < kend; k0 += BK) {
        __syncthreads();   // protects LDS from previous iter/job readers
        if (A_MK) {
            As[kq + 0][lrow] = av.x; As[kq + 1][lrow] = av.y;
            As[kq + 2][lrow] = av.z; As[kq + 3][lrow] = av.w;
        } else {
            *(float4*)&As[kk][cc] = av;
        }
        Bs[kq + 0][lrow] = bv.x; Bs[kq + 1][lrow] = bv.y;
        Bs[kq + 2][lrow] = bv.z; Bs[kq + 3][lrow] = bv.w;
        __syncthreads();
        const int k1 = k0 + BK;
        if (k1 < kend) {   // prefetch next slab (registers only; no LDS hazard)
            if (A_MK) av = *(const float4*)(A + (size_t)(m0 + lrow) * lda + k1 + kq);
            else      av = *(const float4*)(A + (size_t)(k1 + kk) * lda + m0 + cc);
            if (!GN || (n0 + lrow) < N)
                bv = *(const float4*)(Bm + (size_t)(n0 + lrow) * ldb + k1 + kq);
        }
#pragma unroll
        for (int k = 0; k < BK; ++k) {
            const float4 a4 = *(const float4*)&As[k][ty * 4];
            const float4 b4 = *(const float4*)&Bs[k][tx * 4];
            const float a_[4] = {a4.x, a4.y, a4.z, a4.w};
            const float b_[4] = {b4.x, b4.y, b4.z, b4.w};
#pragma unroll
            for (int i = 0; i < 4; ++i)
#pragma unroll
                for (int j = 0; j < 4; ++j)
                    acc[i][j] = fmaf(a_[i], b_[j], acc[i][j]);
        }
    }
#pragma unroll
    for (int i = 0; i < 4; ++i) {
        const int gm = m0 + ty * 4 + i;
        const int gn = n0 + tx * 4;
        if (!GN || gn < N)
            *(float4*)(C + (size_t)gm * ldc + gn) =
                make_float4(acc[i][0], acc[i][1], acc[i][2], acc[i][3]);
    }
}

// ---------------------------------------------------------------------------
// Fused aux+scan chunk (shared by mega kernel and fallback scan_k).
// One wave per (b,d); lane = state n.  See previous session notes.
// ---------------------------------------------------------------------------
template<int CNT>
__device__ __forceinline__ void scan_chunk(const float* __restrict__ dBC,
                                           const float* __restrict__ xzT,
                                           const float* __restrict__ ixT,
                                           float* __restrict__ gT,
                                           float4* __restrict__ aux_w,
                                           float (*__restrict__ Pw)[65],
                                           const int d, const int base, const int t0,
                                           const float An2, const float4 wdt,
                                           const float bdt, const float dpv,
                                           const int lane, float& h) {
    if (lane < CNT) {
        const int tok = base + t0 + lane;
        const float4 dt4 = *(const float4*)(dBC + (size_t)tok * NDBC);
        float s = fmaf(dt4.x, wdt.x, bdt);
        s = fmaf(dt4.y, wdt.y, s);
        s = fmaf(dt4.z, wdt.z, s);
        s = fmaf(dt4.w, wdt.w, s);
        const float delta = fmaxf(s, 0.f) + __logf(1.f + __expf(-fabsf(s)));
        const float ixv = ixT[(size_t)d * NTOK + tok];
        const float zv  = xzT[(size_t)(D_INNER + d) * NTOK + tok];
        const float sz  = zv * __builtin_amdgcn_rcpf(1.f + __expf(-zv));
        aux_w[lane] = make_float4(delta, delta * ixv, dpv * ixv, sz);
    }
#pragma unroll 8
    for (int i = 0; i < CNT; ++i) {
        const size_t rb = (size_t)(base + t0 + i) * NDBC;
        const float Bv = dBC[rb + DT_RANK + lane];                 // coalesced, L2-hot
        const float Cv = dBC[rb + DT_RANK + D_STATE + lane];
        const float4 a4 = aux_w[i];                                // LDS broadcast
        const float dA = __builtin_amdgcn_exp2f(a4.x * An2);       // exp(delta*A)
        h = fmaf(dA, h, a4.y * Bv);
        Pw[i][lane] = h * Cv;
    }
    const int tl = lane & 31, hf = lane >> 5;
    float s2 = 0.f;
    if (tl < CNT) {
#pragma unroll
        for (int j = 0; j < 32; ++j) s2 += Pw[tl][hf * 32 + j];    // 2-way banks: free
    }
    s2 += __shfl_xor(s2, 32, 64);
    if (hf == 0 && tl < CNT) {
        const float4 a4 = aux_w[tl];
        gT[(size_t)d * NTOK + base + t0 + tl] = (s2 + a4.z) * a4.w;  // coalesced
    }
}

// ---------------------------------------------------------------------------
// Mega kernel: whole Mamba block in one cooperative launch.
// Phases:  gemm1 | conv+silu | gemm2(splitK8) | reduce8 | scan | gemm3(splitK8) | reduce8
// LDS: union of GEMM staging (8.7 KB) and scan buffers (35.3 KB) -> 35328 B.
// __launch_bounds__(256,4): VGPR<=128 + LDS 35 KB => 4 blocks/CU guaranteed,
// so a 1024-block cooperative grid is always co-resident. All phases are
// grid-stride, so any smaller grid (from the occupancy query) stays correct.
// ---------------------------------------------------------------------------
union MegaSmem {
    struct { float As[BK][BM + 4]; float Bs[BK][BN + 4]; } g;   // 8704 B
    struct { float4 aux[4][32]; float P[4][32][65]; } s;        // 35328 B
};

__global__ __launch_bounds__(256, 4) void mega_k(
    const float* __restrict__ x,      const float* __restrict__ W_in,
    const float* __restrict__ conv_w, const float* __restrict__ conv_b,
    const float* __restrict__ W_x,    const float* __restrict__ W_dt,
    const float* __restrict__ b_dt,   const float* __restrict__ A_log,
    const float* __restrict__ Dp,     const float* __restrict__ W_out,
    float* __restrict__ out,          float* __restrict__ ws) {
    __shared__ MegaSmem sm;
    cg::grid_group grid = cg::this_grid();
    const int tid = threadIdx.x;
    const int bid = blockIdx.x;
    const int nb  = gridDim.x;

    float* xzT = ws;                    // [1024][1152]
    float* ixT = xzT + 1179648;         // [512][1152]
    float* dBC = ixT + 589824;          // [1152][132]
    float* gT  = dBC + 152064;          // [512][1152]
    float* sl3 = gT + 589824;           // 8 x [1152][132]
    float* sl6 = sl3 + 8 * 152064;      // 8 x [1152][256]

    // P1: xzT[e][tok] = W_in · x   (M=1024, N=1152, K=256) -- 288 tiles
    for (int job = bid; job < 288; job += nb)
        gemm_tile<true, false>(W_in, x, xzT, NTOK, D_MODEL, D_MODEL, NTOK,
                               (job / 18) * BM, (job % 18) * BN, 0, D_MODEL,
                               sm.g.As, sm.g.Bs, tid);
    grid.sync();

    // P2: depthwise conv(4) + SiLU -> ixT[d][tok]
    for (int idx = bid * 256 + tid; idx < D_INNER * NTOK; idx += nb * 256) {
        const int dd = idx / NTOK, tok = idx - dd * NTOK;
        const int bb = tok / L_SEQ, t = tok - bb * L_SEQ;
        const float* row = xzT + (size_t)dd * NTOK + tok;
        const float4 wv = *(const float4*)(conv_w + dd * 4);
        float s = conv_b[dd];
        if (t >= 2) s = fmaf(wv.x, row[-2], s);
        if (t >= 1) s = fmaf(wv.y, row[-1], s);
        s = fmaf(wv.z, row[0], s);
        if (t < L_SEQ - 1) s = fmaf(wv.w, row[1], s);
        ixT[idx] = s * __builtin_amdgcn_rcpf(1.f + __expf(-s));
    }
    grid.sync();

    // P3: dBC slabs (M=1152, N=132, K=512) split-K=8 (kslab 64) -- 432 jobs
    for (int job = bid; job < 432; job += nb) {
        const int sK = job / 54, r = job % 54;
        gemm_tile<false, true>(ixT, W_x, sl3 + (size_t)sK * 152064, NDBC,
                               NTOK, D_INNER, NDBC,
                               (r / 3) * BM, (r % 3) * BN, sK * 64, sK * 64 + 64,
                               sm.g.As, sm.g.Bs, tid);
    }
    grid.sync();

    // P4: reduce 8 slabs -> dBC (38016 float4)
    {
        const float4* in4 = (const float4*)sl3;
        float4* o4 = (float4*)dBC;
        for (int i = bid * 256 + tid; i < 38016; i += nb * 256) {
            float4 a = in4[i];
#pragma unroll
            for (int sK = 1; sK < 8; ++sK) {
                const float4 bb = in4[i + sK * 38016];
                a.x += bb.x; a.y += bb.y; a.z += bb.z; a.w += bb.w;
            }
            o4[i] = a;
        }
    }
    grid.sync();

    // P5: fused aux + selective scan -> gT   (1024 units, 1:1 with blocks)
    {
        const int w = tid >> 6, lane = tid & 63;
        for (int unit = bid; unit < B_SZ * 128; unit += nb) {
            const int bb = unit >> 7, dg = unit & 127;
            const int d = (dg << 2) | w;
            const int base = bb * L_SEQ;
            const float An2 = -__expf(A_log[(d << 6) + lane]) * 1.44269504088896f;
            const float4 wdt = *(const float4*)(W_dt + (d << 2));
            const float bdt = b_dt[d], dpv = Dp[d];
            float h = 0.f;
            scan_chunk<32>(dBC, xzT, ixT, gT, sm.s.aux[w], sm.s.P[w], d, base, 0,   An2, wdt, bdt, dpv, lane, h);
            scan_chunk<32>(dBC, xzT, ixT, gT, sm.s.aux[w], sm.s.P[w], d, base, 32,  An2, wdt, bdt, dpv, lane, h);
            scan_chunk<32>(dBC, xzT, ixT, gT, sm.s.aux[w], sm.s.P[w], d, base, 64,  An2, wdt, bdt, dpv, lane, h);
            scan_chunk<32>(dBC, xzT, ixT, gT, sm.s.aux[w], sm.s.P[w], d, base, 96,  An2, wdt, bdt, dpv, lane, h);
            scan_chunk<16>(dBC, xzT, ixT, gT, sm.s.aux[w], sm.s.P[w], d, base, 128, An2, wdt, bdt, dpv, lane, h);
        }
    }
    grid.sync();

    // P6: out slabs (M=1152, N=256, K=512) split-K=8 (kslab 64) -- 576 jobs
    for (int job = bid; job < 576; job += nb) {
        const int sK = job / 72, r = job % 72;
        gemm_tile<false, false>(gT, W_out, sl6 + (size_t)sK * 294912, D_MODEL,
                                NTOK, D_INNER, D_MODEL,
                                (r / 4) * BM, (r % 4) * BN, sK * 64, sK * 64 + 64,
                                sm.g.As, sm.g.Bs, tid);
    }
    grid.sync();

    // P7: reduce 8 slabs -> out (73728 float4)
    {
        const float4* in4 = (const float4*)sl6;
        float4* o4 = (float4*)out;
        for (int i = bid * 256 + tid; i < 73728; i += nb * 256) {
            float4 a = in4[i];
#pragma unroll
            for (int sK = 1; sK < 8; ++sK) {
                const float4 bb = in4[i + sK * 73728];
                a.x += bb.x; a.y += bb.y; a.z += bb.z; a.w += bb.w;
            }
            o4[i] = a;
        }
    }
}

// ---------------------------------------------------------------------------
// Fallback pipeline (previous verified 7-kernel version), used only if the
// cooperative launch is rejected cleanly.
// ---------------------------------------------------------------------------
template<bool A_MK, bool GN>
__global__ __launch_bounds__(256) void gemm_k2(const float* __restrict__ A,
                                               const float* __restrict__ Bm,
                                               float* __restrict__ C,
                                               const int N, const int lda, const int ldb,
                                               const int ldc, const int kslab,
                                               const size_t sstride) {
    __shared__ float As[BK][BM + 4];
    __shared__ float Bs[BK][BN + 4];
    gemm_tile<A_MK, GN>(A, Bm, C + (size_t)blockIdx.z * sstride, N, lda, ldb, ldc,
                        blockIdx.y * BM, blockIdx.x * BN,
                        blockIdx.z * kslab, blockIdx.z * kslab + kslab,
                        As, Bs, (int)threadIdx.x);
}

__global__ __launch_bounds__(256) void reduce4_k(const float4* __restrict__ in,
                                                 float4* __restrict__ out,
                                                 const int n4, const int s4) {
    const int i = blockIdx.x * 256 + threadIdx.x;
    if (i >= n4) return;
    const float4 a = in[i], b = in[i + s4], c = in[i + 2 * s4], d = in[i + 3 * s4];
    out[i] = make_float4(a.x + b.x + c.x + d.x, a.y + b.y + c.y + d.y,
                         a.z + b.z + c.z + d.z, a.w + b.w + c.w + d.w);
}

__global__ __launch_bounds__(128) void conv_k(const float* __restrict__ xzT,
                                              const float* __restrict__ cw,
                                              const float* __restrict__ cb,
                                              float* __restrict__ ixT) {
    const int tok = blockIdx.x * 128 + threadIdx.x;
    const int d = blockIdx.y;
    const int b = tok / L_SEQ;
    const int t = tok - b * L_SEQ;
    const float* row = xzT + (size_t)d * NTOK + tok;
    const float4 w = *(const float4*)(cw + d * 4);
    float s = cb[d];
    if (t >= 2) s = fmaf(w.x, row[-2], s);
    if (t >= 1) s = fmaf(w.y, row[-1], s);
    s = fmaf(w.z, row[0], s);
    if (t < L_SEQ - 1) s = fmaf(w.w, row[1], s);
    ixT[(size_t)d * NTOK + tok] = s * __builtin_amdgcn_rcpf(1.f + __expf(-s));
}

__global__ __launch_bounds__(256) void scan_k(const float* __restrict__ dBC,
                                              const float* __restrict__ xzT,
                                              const float* __restrict__ ixT,
                                              const float* __restrict__ W_dt,
                                              const float* __restrict__ b_dt,
                                              const float* __restrict__ A_log,
                                              const float* __restrict__ Dp,
                                              float* __restrict__ gT) {
    __shared__ float4 aux_s[4][32];
    __shared__ float P[4][32][65];
    const int w = threadIdx.x >> 6, lane = threadIdx.x & 63;
    const int b = blockIdx.x >> 7, dg = blockIdx.x & 127;
    const int d = (dg << 2) | w;
    const int base = b * L_SEQ;
    const float An2 = -__expf(A_log[(d << 6) + lane]) * 1.44269504088896f;
    const float4 wdt = *(const float4*)(W_dt + (d << 2));
    const float bdt = b_dt[d], dpv = Dp[d];
    float h = 0.f;
    scan_chunk<32>(dBC, xzT, ixT, gT, aux_s[w], P[w], d, base, 0,   An2, wdt, bdt, dpv, lane, h);
    scan_chunk<32>(dBC, xzT, ixT, gT, aux_s[w], P[w], d, base, 32,  An2, wdt, bdt, dpv, lane, h);
    scan_chunk<32>(dBC, xzT, ixT, gT, aux_s[w], P[w], d, base, 64,  An2, wdt, bdt, dpv, lane, h);
    scan_chunk<32>(dBC, xzT, ixT, gT, aux_s[w], P[w], d, base, 96,  An2, wdt, bdt, dpv, lane, h);
    scan_chunk<16>(dBC, xzT, ixT, gT, aux_s[w], P[w], d, base, 128, An2, wdt, bdt, dpv, lane, h);
}

// ---------------------------------------------------------------------------
extern "C" void kernel_launch(void* const* d_in, const int* in_sizes, int n_in,
                              void* d_out, int out_size, void* d_ws, size_t ws_size,
                              hipStream_t stream) {
    const float* x      = (const float*)d_in[0];
    // d_in[1] = lastin (unused: reference starts from h0 = 0)
    const float* W_in   = (const float*)d_in[2];
    const float* conv_w = (const float*)d_in[3];
    const float* conv_b = (const float*)d_in[4];
    const float* W_x    = (const float*)d_in[5];
    const float* W_dt   = (const float*)d_in[6];
    const float* b_dt   = (const float*)d_in[7];
    const float* A_log  = (const float*)d_in[8];
    const float* Dp     = (const float*)d_in[9];
    const float* W_out  = (const float*)d_in[10];
    float* out = (float*)d_out;
    float* ws  = (float*)d_ws;

    static int grid = -1;
    if (grid < 0) {
        int occ = 0;
        if (hipOccupancyMaxActiveBlocksPerMultiprocessor(&occ, (const void*)mega_k,
                                                         256, 0) != hipSuccess || occ < 1)
            occ = 1;
        int dev = 0;
        hipGetDevice(&dev);
        int nCU = 0;
        if (hipDeviceGetAttribute(&nCU, hipDeviceAttributeMultiprocessorCount, dev)
                != hipSuccess || nCU < 1)
            nCU = 256;
        long g = (long)occ * (long)nCU;
        grid = (int)(g > 1024 ? 1024 : g);
        if (grid < 1) grid = 256;
    }

    void* args[] = { (void*)&x, (void*)&W_in, (void*)&conv_w, (void*)&conv_b,
                     (void*)&W_x, (void*)&W_dt, (void*)&b_dt, (void*)&A_log,
                     (void*)&Dp, (void*)&W_out, (void*)&out, (void*)&ws };
    if (hipLaunchCooperativeKernel((const void*)mega_k, dim3(grid), dim3(256),
                                   args, 0, stream) == hipSuccess)
        return;

    // ---- fallback: previous verified 7-kernel pipeline ----
    float* xzT = ws;
    float* ixT = xzT + 1179648;
    float* dBC = ixT + 589824;
    float* gT  = dBC + 152064;
    float* sl3 = gT + 589824;
    float* sl6 = sl3 + 8 * 152064;

    gemm_k2<true, false><<<dim3(18, 16, 1), 256, 0, stream>>>(
        W_in, x, xzT, NTOK, D_MODEL, D_MODEL, NTOK, D_MODEL, 0);
    conv_k<<<dim3(9, D_INNER), 128, 0, stream>>>(xzT, conv_w, conv_b, ixT);
    gemm_k2<false, true><<<dim3(3, 18, 4), 256, 0, stream>>>(
        ixT, W_x, sl3, NDBC, NTOK, D_INNER, NDBC, 128, (size_t)NTOK * NDBC);
    reduce4_k<<<dim3(149), 256, 0, stream>>>((const float4*)sl3, (float4*)dBC,
                                             38016, 38016);
    scan_k<<<dim3(B_SZ * 128), 256, 0, stream>>>(dBC, xzT, ixT, W_dt, b_dt, A_log, Dp, gT);
    gemm_k2<false, false><<<dim3(4, 18, 4), 256, 0, stream>>>(
        gT, W_out, sl6, D_MODEL, NTOK, D_INNER, D_MODEL, 128, (size_t)NTOK * D_MODEL);
    reduce4_k<<<dim3(288), 256, 0, stream>>>((const float4*)sl6, (float4*)out,
                                             73728, 73728);
}

// Round 2
// 138.682 us; speedup vs baseline: 3.6126x; 3.6126x over previous
//
#include <hip/hip_runtime.h>

#define B_SZ 8
#define L_SEQ 144
#define NTOK 1152
#define D_MODEL 256
#define D_INNER 512
#define D_STATE 64
#define DT_RANK 4
#define NDBC 132

#define BM 64
#define BN 64
#define BK 16

// ---------------------------------------------------------------------------
// Tiled GEMM with register double-buffer (prefetch next k-slab before FMA):
//  A_MK=true : A stored [m][k] (row stride lda) | false: A stored [k][m]
//  B always stored [n][k] (row stride ldb)
//  GN        : guard n<N on B-loads and C-stores (N=132 case)
//  CONV      : (A_MK=false only) A rows are pre-conv xzT[d][tok]; apply
//              depthwise conv(4)+SiLU on the fly while staging to LDS.
//              Bitwise-identical to the standalone conv kernel (same fmaf
//              order; missing taps folded as fmaf(w,0,s)==s).
// Split-K: blockIdx.z selects k-slab; C advanced by z*sstride.
// ---------------------------------------------------------------------------
template<bool A_MK, bool GN, bool CONV>
__global__ __launch_bounds__(256) void gemm_k(const float* __restrict__ A,
                                              const float* __restrict__ Bm,
                                              float* __restrict__ C,
                                              const int N, const int lda, const int ldb,
                                              const int ldc,
                                              const float* __restrict__ cw,
                                              const float* __restrict__ cb,
                                              const int kslab, const size_t sstride) {
    __shared__ float As[BK][BM + 4];
    __shared__ float Bs[BK][BN + 4];
    const int tid = threadIdx.x;
    const int m0 = blockIdx.y * BM;
    const int n0 = blockIdx.x * BN;
    const int kbeg = blockIdx.z * kslab;
    const int kend = kbeg + kslab;
    const int ty = tid >> 4, tx = tid & 15;
    const int lrow = tid >> 2, kq = (tid & 3) * 4;   // transpose-load indices
    const int kk = tid >> 4, cc = (tid & 15) * 4;    // direct-load indices
    float acc[4][4] = {};
    float4 av, bv, cw4;
    float xm2 = 0.f, xm1 = 0.f, xp4 = 0.f, cbv = 0.f;

    auto loadA = [&](const int k0) {
        if (A_MK) {
            av = *(const float4*)(A + (size_t)(m0 + lrow) * lda + k0 + kq);
        } else {
            const float* row = A + (size_t)(k0 + kk) * lda + m0 + cc;
            av = *(const float4*)row;
            if (CONV) {
                const int t = (m0 + cc) % L_SEQ;   // tok group base within sequence
                xm2 = (t > 0) ? row[-2] : 0.f;     // t==0: left pad (2 zeros)
                xm1 = (t > 0) ? row[-1] : 0.f;
                xp4 = (t < L_SEQ - 4) ? row[4] : 0.f;  // t==140: right pad (1 zero)
                cw4 = *(const float4*)(cw + (k0 + kk) * 4);
                cbv = cb[k0 + kk];
            }
        }
        if (!GN || (n0 + lrow) < N)
            bv = *(const float4*)(Bm + (size_t)(n0 + lrow) * ldb + k0 + kq);
    };

    auto storeLDS = [&]() {
        if (A_MK) {
            As[kq + 0][lrow] = av.x; As[kq + 1][lrow] = av.y;
            As[kq + 2][lrow] = av.z; As[kq + 3][lrow] = av.w;
        } else if (CONV) {
            const float in7[7] = {xm2, xm1, av.x, av.y, av.z, av.w, xp4};
            float4 o;
            float* op = &o.x;
#pragma unroll
            for (int j = 0; j < 4; ++j) {
                float s = cbv;
                s = fmaf(cw4.x, in7[j + 0], s);
                s = fmaf(cw4.y, in7[j + 1], s);
                s = fmaf(cw4.z, in7[j + 2], s);
                s = fmaf(cw4.w, in7[j + 3], s);
                op[j] = s * __builtin_amdgcn_rcpf(1.f + __expf(-s));
            }
            *(float4*)&As[kk][cc] = o;
        } else {
            *(float4*)&As[kk][cc] = av;
        }
        Bs[kq + 0][lrow] = bv.x; Bs[kq + 1][lrow] = bv.y;
        Bs[kq + 2][lrow] = bv.z; Bs[kq + 3][lrow] = bv.w;
    };

    bv = make_float4(0.f, 0.f, 0.f, 0.f);
    loadA(kbeg);
    for (int k0 = kbeg; k0 < kend; k0 += BK) {
        __syncthreads();
        storeLDS();
        __syncthreads();
        if (k0 + BK < kend) loadA(k0 + BK);   // prefetch: regs only, no LDS hazard
#pragma unroll
        for (int k = 0; k < BK; ++k) {
            const float4 a4 = *(const float4*)&As[k][ty * 4];
            const float4 b4 = *(const float4*)&Bs[k][tx * 4];
            const float a_[4] = {a4.x, a4.y, a4.z, a4.w};
            const float b_[4] = {b4.x, b4.y, b4.z, b4.w};
#pragma unroll
            for (int i = 0; i < 4; ++i)
#pragma unroll
                for (int j = 0; j < 4; ++j)
                    acc[i][j] = fmaf(a_[i], b_[j], acc[i][j]);
        }
    }
    C += (size_t)blockIdx.z * sstride;
#pragma unroll
    for (int i = 0; i < 4; ++i) {
        const int gm = m0 + ty * 4 + i;
        const int gn = n0 + tx * 4;
        if (!GN || gn < N)
            *(float4*)(C + (size_t)gm * ldc + gn) =
                make_float4(acc[i][0], acc[i][1], acc[i][2], acc[i][3]);
    }
}

// ---------------------------------------------------------------------------
// Split-K slab reduction: out[i] = sum_{s<4} in[i + s*s4], float4-wide
// ---------------------------------------------------------------------------
__global__ __launch_bounds__(256) void reduce4_k(const float4* __restrict__ in,
                                                 float4* __restrict__ out,
                                                 const int n4, const int s4) {
    const int i = blockIdx.x * 256 + threadIdx.x;
    if (i >= n4) return;
    const float4 a = in[i], b = in[i + s4], c = in[i + 2 * s4], d = in[i + 3 * s4];
    out[i] = make_float4(a.x + b.x + c.x + d.x, a.y + b.y + c.y + d.y,
                         a.z + b.z + c.z + d.z, a.w + b.w + c.w + d.w);
}

// ---------------------------------------------------------------------------
// Fused aux+scan. One wave per (b,d); lane = state n. Per 32-token chunk:
//   pre-pass (lane-parallel): recompute conv+SiLU (ix) from xzT, then
//     delta=softplus(dt·Wdt+b), delta*ix, Dp*ix, silu(z)
//   serial : h = exp2(delta*An2)*h + (delta*ix)*B[t][n];  P[t][n] = h*C[t][n]
//   reduce : transposed LDS row-sum (half-row per lane + shfl_xor 32)
// No __syncthreads: each wave owns its own aux/P LDS slice.
// ---------------------------------------------------------------------------
template<int CNT>
__device__ __forceinline__ void scan_chunk(const float* __restrict__ dBC,
                                           const float* __restrict__ xzT,
                                           float* __restrict__ gT,
                                           float4* __restrict__ aux_w,
                                           float (*__restrict__ Pw)[65],
                                           const int d, const int base, const int t0,
                                           const float An2, const float4 wdt,
                                           const float bdt, const float dpv,
                                           const float4 cw4, const float cbv,
                                           const int lane, float& h) {
    if (lane < CNT) {
        const int t = t0 + lane;
        const int tok = base + t;
        // conv(4)+SiLU recompute (bitwise-identical to the old conv kernel)
        const float* row = xzT + (size_t)d * NTOK + tok;
        float s0 = cbv;
        if (t >= 2) s0 = fmaf(cw4.x, row[-2], s0);
        if (t >= 1) s0 = fmaf(cw4.y, row[-1], s0);
        s0 = fmaf(cw4.z, row[0], s0);
        if (t < L_SEQ - 1) s0 = fmaf(cw4.w, row[1], s0);
        const float ixv = s0 * __builtin_amdgcn_rcpf(1.f + __expf(-s0));

        const float4 dt4 = *(const float4*)(dBC + (size_t)tok * NDBC);
        float s = fmaf(dt4.x, wdt.x, bdt);
        s = fmaf(dt4.y, wdt.y, s);
        s = fmaf(dt4.z, wdt.z, s);
        s = fmaf(dt4.w, wdt.w, s);
        const float delta = fmaxf(s, 0.f) + __logf(1.f + __expf(-fabsf(s)));
        const float zv = xzT[(size_t)(D_INNER + d) * NTOK + tok];
        const float sz = zv * __builtin_amdgcn_rcpf(1.f + __expf(-zv));
        aux_w[lane] = make_float4(delta, delta * ixv, dpv * ixv, sz);
    }
#pragma unroll 8
    for (int i = 0; i < CNT; ++i) {
        const size_t rb = (size_t)(base + t0 + i) * NDBC;
        const float Bv = dBC[rb + DT_RANK + lane];                 // coalesced, L2-hot
        const float Cv = dBC[rb + DT_RANK + D_STATE + lane];
        const float4 a4 = aux_w[i];                                // LDS broadcast
        const float dA = __builtin_amdgcn_exp2f(a4.x * An2);       // exp(delta*A)
        h = fmaf(dA, h, a4.y * Bv);
        Pw[i][lane] = h * Cv;
    }
    const int tl = lane & 31, hf = lane >> 5;
    float s2 = 0.f;
    if (tl < CNT) {
#pragma unroll
        for (int j = 0; j < 32; ++j) s2 += Pw[tl][hf * 32 + j];    // 2-way banks: free
    }
    s2 += __shfl_xor(s2, 32, 64);
    if (hf == 0 && tl < CNT) {
        const float4 a4 = aux_w[tl];
        gT[(size_t)d * NTOK + base + t0 + tl] = (s2 + a4.z) * a4.w;  // coalesced
    }
}

__global__ __launch_bounds__(256) void scan_k(const float* __restrict__ dBC,
                                              const float* __restrict__ xzT,
                                              const float* __restrict__ W_dt,
                                              const float* __restrict__ b_dt,
                                              const float* __restrict__ A_log,
                                              const float* __restrict__ Dp,
                                              const float* __restrict__ conv_w,
                                              const float* __restrict__ conv_b,
                                              float* __restrict__ gT) {
    __shared__ float4 aux_s[4][32];
    __shared__ float P[4][32][65];
    const int w = threadIdx.x >> 6, lane = threadIdx.x & 63;
    const int b = blockIdx.x >> 7, dg = blockIdx.x & 127;
    const int d = (dg << 2) | w;
    const int base = b * L_SEQ;
    const float An2 = -__expf(A_log[(d << 6) + lane]) * 1.44269504088896f;
    const float4 wdt = *(const float4*)(W_dt + (d << 2));
    const float bdt = b_dt[d], dpv = Dp[d];
    const float4 cw4 = *(const float4*)(conv_w + (d << 2));
    const float cbv = conv_b[d];
    float h = 0.f;
    scan_chunk<32>(dBC, xzT, gT, aux_s[w], P[w], d, base, 0,   An2, wdt, bdt, dpv, cw4, cbv, lane, h);
    scan_chunk<32>(dBC, xzT, gT, aux_s[w], P[w], d, base, 32,  An2, wdt, bdt, dpv, cw4, cbv, lane, h);
    scan_chunk<32>(dBC, xzT, gT, aux_s[w], P[w], d, base, 64,  An2, wdt, bdt, dpv, cw4, cbv, lane, h);
    scan_chunk<32>(dBC, xzT, gT, aux_s[w], P[w], d, base, 96,  An2, wdt, bdt, dpv, cw4, cbv, lane, h);
    scan_chunk<16>(dBC, xzT, gT, aux_s[w], P[w], d, base, 128, An2, wdt, bdt, dpv, cw4, cbv, lane, h);
}

// ---------------------------------------------------------------------------
extern "C" void kernel_launch(void* const* d_in, const int* in_sizes, int n_in,
                              void* d_out, int out_size, void* d_ws, size_t ws_size,
                              hipStream_t stream) {
    const float* x      = (const float*)d_in[0];
    // d_in[1] = lastin (unused: reference starts from h0 = 0)
    const float* W_in   = (const float*)d_in[2];
    const float* conv_w = (const float*)d_in[3];
    const float* conv_b = (const float*)d_in[4];
    const float* W_x    = (const float*)d_in[5];
    const float* W_dt   = (const float*)d_in[6];
    const float* b_dt   = (const float*)d_in[7];
    const float* A_log  = (const float*)d_in[8];
    const float* Dp     = (const float*)d_in[9];
    const float* W_out  = (const float*)d_in[10];
    float* out = (float*)d_out;

    float* ws  = (float*)d_ws;
    float* xzT = ws;                    // [1024][1152] = 1,179,648 f
    float* dBC = xzT + 1179648;         // [1152][132]  =   152,064 f
    float* gT  = dBC + 152064;          // [512][1152]  =   589,824 f
    float* sl3 = gT + 589824;           // 4×152,064    =   608,256 f
    float* sl6 = xzT;                   // reuse: xzT dead after scan (4×294,912 fits)

    // 1) xzT[e][tok] = W_in[e][:] · x[tok][:]   (M=1024, N=1152, K=256)
    gemm_k<true, false, false><<<dim3(18, 16, 1), 256, 0, stream>>>(
        W_in, x, xzT, NTOK, D_MODEL, D_MODEL, NTOK, nullptr, nullptr, D_MODEL, 0);
    // 2) dBC[tok][e] = silu(conv(xz))[tok][:] · W_x[e][:]  (conv fused into A-load)
    //    M=1152, N=132, K=512, split-K=4
    gemm_k<false, true, true><<<dim3(3, 18, 4), 256, 0, stream>>>(
        xzT, W_x, sl3, NDBC, NTOK, D_INNER, NDBC, conv_w, conv_b, 128,
        (size_t)NTOK * NDBC);
    reduce4_k<<<dim3(149), 256, 0, stream>>>((const float4*)sl3, (float4*)dBC,
                                             NTOK * NDBC / 4, NTOK * NDBC / 4);
    // 3) fused conv + aux + selective scan -> gT[d][tok]
    scan_k<<<dim3(B_SZ * 128), 256, 0, stream>>>(dBC, xzT, W_dt, b_dt, A_log, Dp,
                                                 conv_w, conv_b, gT);
    // 4) out[tok][e] = g[tok][:] · W_out[e][:]  (M=1152, N=256, K=512) split-K=4
    gemm_k<false, false, false><<<dim3(4, 18, 4), 256, 0, stream>>>(
        gT, W_out, sl6, D_MODEL, NTOK, D_INNER, D_MODEL, nullptr, nullptr, 128,
        (size_t)NTOK * D_MODEL);
    reduce4_k<<<dim3(288), 256, 0, stream>>>((const float4*)sl6, (float4*)out,
                                             NTOK * D_MODEL / 4, NTOK * D_MODEL / 4);
}